// Round 1
// baseline (311.845 us; speedup 1.0000x reference)
//
#include <hip/hip_runtime.h>
#include <hip/hip_bf16.h>

#define E_N 8
#define D_DIM 1024
#define F_DIM 2048
#define T_N 2048
#define BM 128
#define BN 128
#define BK 32
#define LDP 40   // padded LDS row length in bf16 (32 + 8) -> 80B stride, 16B aligned

typedef unsigned short u16;
typedef unsigned int u32;
typedef float floatx4 __attribute__((ext_vector_type(4)));
typedef short bf16x8v __attribute__((ext_vector_type(8)));

__device__ __forceinline__ u16 f2bf(float f) {
    union { float f; u32 u; } v; v.f = f;
    u32 r = v.u + 0x7FFFu + ((v.u >> 16) & 1u);   // RNE
    return (u16)(r >> 16);
}

// ---------------- Router: softmax -> top2 -> renorm, bucket by expert ----------------
__global__ void router_kernel(const float* __restrict__ gl,
                              int* __restrict__ cnt, int* __restrict__ base,
                              int* __restrict__ slot_tok, int* __restrict__ tok_slot,
                              float* __restrict__ tok_w) {
    __shared__ int scnt[E_N];
    __shared__ int sbase[E_N];
    const int tid = threadIdx.x;
    if (tid < E_N) scnt[tid] = 0;
    __syncthreads();
    int e0a[8], e1a[8], p0a[8], p1a[8];
    float w0a[8];
#pragma unroll
    for (int i = 0; i < 8; ++i) {
        const int t = tid + i * 256;
        const float4* gp = (const float4*)(gl + (size_t)t * E_N);
        const float4 x0 = gp[0], x1 = gp[1];
        float l[E_N] = {x0.x, x0.y, x0.z, x0.w, x1.x, x1.y, x1.z, x1.w};
        int e0 = 0; float m0 = l[0];
#pragma unroll
        for (int e = 1; e < E_N; ++e) if (l[e] > m0) { m0 = l[e]; e0 = e; }
        int e1 = -1; float m1 = -1e30f;
#pragma unroll
        for (int e = 0; e < E_N; ++e) if (e != e0 && l[e] > m1) { m1 = l[e]; e1 = e; }
        const float p = __expf(m1 - m0);       // <= 1
        w0a[i] = 1.0f / (1.0f + p);
        e0a[i] = e0; e1a[i] = e1;
        p0a[i] = atomicAdd(&scnt[e0], 1);
        p1a[i] = atomicAdd(&scnt[e1], 1);
    }
    __syncthreads();
    if (tid == 0) {
        int s = 0;
        for (int e = 0; e < E_N; ++e) { sbase[e] = s; base[e] = s; cnt[e] = scnt[e]; s += scnt[e]; }
    }
    __syncthreads();
#pragma unroll
    for (int i = 0; i < 8; ++i) {
        const int t = tid + i * 256;
        const int s0 = sbase[e0a[i]] + p0a[i];
        const int s1 = sbase[e1a[i]] + p1a[i];
        slot_tok[s0] = t; slot_tok[s1] = t;
        tok_slot[2 * t] = s0; tok_slot[2 * t + 1] = s1;
        tok_w[2 * t] = w0a[i]; tok_w[2 * t + 1] = 1.0f - w0a[i];
    }
}

// ---------------- GEMM1: h = silu(X_gather @ W1[e]), bf16 out ----------------
__global__ __launch_bounds__(256)
void gemm1_kernel(const float* __restrict__ X, const float* __restrict__ W1,
                  const int* __restrict__ cnt, const int* __restrict__ base,
                  const int* __restrict__ slot_tok, u16* __restrict__ h) {
    const int e = blockIdx.z, mt = blockIdx.y, ft = blockIdx.x;
    const int cnt_e = cnt[e];
    if (mt * BM >= cnt_e) return;
    const int base_e = base[e];
    __shared__ __align__(16) u16 Alds[BM][LDP];
    __shared__ __align__(16) u16 Blds[BN][LDP];
    const int tid = threadIdx.x;
    // A staging: 2 threads/row, 16 f32 each
    const int ar = tid >> 1, ah = tid & 1;
    const int arow_g = mt * BM + ar;
    const int tok = (arow_g < cnt_e) ? slot_tok[base_e + arow_g] : 0;
    const float* aptr = X + (size_t)tok * D_DIM + ah * 16;
    // B staging: column reads of W1 (coalesced across lanes over f)
    const int bfc = tid & 127, bh = tid >> 7;
    const float* bptr = W1 + (size_t)e * D_DIM * F_DIM + (size_t)(bh * 16) * F_DIM
                        + (size_t)ft * BN + bfc;
    const int wid = tid >> 6, lane = tid & 63;
    const int wm = (wid >> 1) * 64, wn = (wid & 1) * 64;
    const int lr = lane & 15, lk = (lane >> 4) * 8;
    floatx4 acc[4][4];
    const floatx4 zero = {0.f, 0.f, 0.f, 0.f};
#pragma unroll
    for (int i = 0; i < 4; ++i)
#pragma unroll
        for (int j = 0; j < 4; ++j) acc[i][j] = zero;

    for (int kt = 0; kt < D_DIM / BK; ++kt) {
        const int k0 = kt * BK;
        float4 av[4];
#pragma unroll
        for (int c = 0; c < 4; ++c) av[c] = *(const float4*)(aptr + k0 + c * 4);
        float bv[16];
#pragma unroll
        for (int kk = 0; kk < 16; ++kk) bv[kk] = bptr[(size_t)(k0 + kk) * F_DIM];
        __syncthreads();   // prior iter's LDS reads complete
        u32 ua[8], ub[8];
#pragma unroll
        for (int c = 0; c < 4; ++c) {
            ua[2 * c]     = (u32)f2bf(av[c].x) | ((u32)f2bf(av[c].y) << 16);
            ua[2 * c + 1] = (u32)f2bf(av[c].z) | ((u32)f2bf(av[c].w) << 16);
        }
#pragma unroll
        for (int j = 0; j < 8; ++j)
            ub[j] = (u32)f2bf(bv[2 * j]) | ((u32)f2bf(bv[2 * j + 1]) << 16);
        u32* adst = (u32*)&Alds[ar][ah * 16];
        *(uint4*)(adst)     = make_uint4(ua[0], ua[1], ua[2], ua[3]);
        *(uint4*)(adst + 4) = make_uint4(ua[4], ua[5], ua[6], ua[7]);
        u32* bdst = (u32*)&Blds[bfc][bh * 16];
        *(uint4*)(bdst)     = make_uint4(ub[0], ub[1], ub[2], ub[3]);
        *(uint4*)(bdst + 4) = make_uint4(ub[4], ub[5], ub[6], ub[7]);
        __syncthreads();
        bf16x8v afr[4], bfr[4];
#pragma unroll
        for (int mi = 0; mi < 4; ++mi) afr[mi] = *(const bf16x8v*)&Alds[wm + mi * 16 + lr][lk];
#pragma unroll
        for (int ni = 0; ni < 4; ++ni) bfr[ni] = *(const bf16x8v*)&Blds[wn + ni * 16 + lr][lk];
#pragma unroll
        for (int mi = 0; mi < 4; ++mi)
#pragma unroll
            for (int ni = 0; ni < 4; ++ni)
                acc[mi][ni] = __builtin_amdgcn_mfma_f32_16x16x32_bf16(afr[mi], bfr[ni], acc[mi][ni], 0, 0, 0);
    }
    // epilogue: silu -> bf16 h
#pragma unroll
    for (int mi = 0; mi < 4; ++mi) {
#pragma unroll
        for (int r = 0; r < 4; ++r) {
            const int row_t = wm + mi * 16 + ((lane >> 4) << 2) + r;
            const int row_g = mt * BM + row_t;
            if (row_g < cnt_e) {
                u16* hp = h + (size_t)(base_e + row_g) * F_DIM + (size_t)ft * BN + wn + lr;
#pragma unroll
                for (int ni = 0; ni < 4; ++ni) {
                    const float v = acc[mi][ni][r];
                    const float s = v / (1.0f + __expf(-v));
                    hp[ni * 16] = f2bf(s);
                }
            }
        }
    }
}

// ---------------- GEMM2: y = h @ W2[e], f32 out ----------------
__global__ __launch_bounds__(256)
void gemm2_kernel(const u16* __restrict__ h, const float* __restrict__ W2,
                  const int* __restrict__ cnt, const int* __restrict__ base,
                  float* __restrict__ y) {
    const int e = blockIdx.z, mt = blockIdx.y, dt = blockIdx.x;
    const int cnt_e = cnt[e];
    if (mt * BM >= cnt_e) return;
    const int base_e = base[e];
    __shared__ __align__(16) u16 Alds[BM][LDP];
    __shared__ __align__(16) u16 Blds[BN][LDP];
    const int tid = threadIdx.x;
    const int ar = tid >> 1, ah = tid & 1;
    int arow = mt * BM + ar; if (arow >= cnt_e) arow = cnt_e - 1;   // clamp: garbage rows never scattered
    const u16* aptr = h + (size_t)(base_e + arow) * F_DIM + ah * 16;
    const int bfc = tid & 127, bh = tid >> 7;
    const float* bptr = W2 + (size_t)e * F_DIM * D_DIM + (size_t)(bh * 16) * D_DIM
                        + (size_t)dt * BN + bfc;
    const int wid = tid >> 6, lane = tid & 63;
    const int wm = (wid >> 1) * 64, wn = (wid & 1) * 64;
    const int lr = lane & 15, lk = (lane >> 4) * 8;
    floatx4 acc[4][4];
    const floatx4 zero = {0.f, 0.f, 0.f, 0.f};
#pragma unroll
    for (int i = 0; i < 4; ++i)
#pragma unroll
        for (int j = 0; j < 4; ++j) acc[i][j] = zero;

    for (int kt = 0; kt < F_DIM / BK; ++kt) {
        const int k0 = kt * BK;
        const uint4 a0 = *(const uint4*)(aptr + k0);
        const uint4 a1 = *(const uint4*)(aptr + k0 + 8);
        float bv[16];
#pragma unroll
        for (int kk = 0; kk < 16; ++kk) bv[kk] = bptr[(size_t)(k0 + kk) * D_DIM];
        __syncthreads();
        u32 ub[8];
#pragma unroll
        for (int j = 0; j < 8; ++j)
            ub[j] = (u32)f2bf(bv[2 * j]) | ((u32)f2bf(bv[2 * j + 1]) << 16);
        u32* adst = (u32*)&Alds[ar][ah * 16];
        *(uint4*)(adst)     = a0;
        *(uint4*)(adst + 4) = a1;
        u32* bdst = (u32*)&Blds[bfc][bh * 16];
        *(uint4*)(bdst)     = make_uint4(ub[0], ub[1], ub[2], ub[3]);
        *(uint4*)(bdst + 4) = make_uint4(ub[4], ub[5], ub[6], ub[7]);
        __syncthreads();
        bf16x8v afr[4], bfr[4];
#pragma unroll
        for (int mi = 0; mi < 4; ++mi) afr[mi] = *(const bf16x8v*)&Alds[wm + mi * 16 + lr][lk];
#pragma unroll
        for (int ni = 0; ni < 4; ++ni) bfr[ni] = *(const bf16x8v*)&Blds[wn + ni * 16 + lr][lk];
#pragma unroll
        for (int mi = 0; mi < 4; ++mi)
#pragma unroll
            for (int ni = 0; ni < 4; ++ni)
                acc[mi][ni] = __builtin_amdgcn_mfma_f32_16x16x32_bf16(afr[mi], bfr[ni], acc[mi][ni], 0, 0, 0);
    }
#pragma unroll
    for (int mi = 0; mi < 4; ++mi) {
#pragma unroll
        for (int r = 0; r < 4; ++r) {
            const int row_t = wm + mi * 16 + ((lane >> 4) << 2) + r;
            const int row_g = mt * BM + row_t;
            if (row_g < cnt_e) {
                float* yp = y + (size_t)(base_e + row_g) * D_DIM + (size_t)dt * BN + wn + lr;
#pragma unroll
                for (int ni = 0; ni < 4; ++ni) yp[ni * 16] = acc[mi][ni][r];
            }
        }
    }
}

// ---------------- Combine: out[t] = w0*y[s0] + w1*y[s1] ----------------
__global__ void combine_kernel(const float* __restrict__ y, const int* __restrict__ tok_slot,
                               const float* __restrict__ tok_w, float* __restrict__ out) {
    const int t = blockIdx.x, tid = threadIdx.x;
    const int s0 = tok_slot[2 * t], s1 = tok_slot[2 * t + 1];
    const float w0 = tok_w[2 * t], w1 = tok_w[2 * t + 1];
    const float4 a = *(const float4*)(y + (size_t)s0 * D_DIM + tid * 4);
    const float4 b = *(const float4*)(y + (size_t)s1 * D_DIM + tid * 4);
    float4 o;
    o.x = w0 * a.x + w1 * b.x;
    o.y = w0 * a.y + w1 * b.y;
    o.z = w0 * a.z + w1 * b.z;
    o.w = w0 * a.w + w1 * b.w;
    *(float4*)(out + (size_t)t * D_DIM + tid * 4) = o;
}

extern "C" void kernel_launch(void* const* d_in, const int* in_sizes, int n_in,
                              void* d_out, int out_size, void* d_ws, size_t ws_size,
                              hipStream_t stream) {
    const float* hidden = (const float*)d_in[0];   // [B,S,D] f32
    const float* gl     = (const float*)d_in[1];   // [T,E]   f32
    const float* W1     = (const float*)d_in[2];   // [E,D,F] f32
    const float* W2     = (const float*)d_in[3];   // [E,F,D] f32
    float* out = (float*)d_out;

    char* ws = (char*)d_ws;
    int* cnt      = (int*)ws;          // 8
    int* basep    = cnt + 8;           // 8
    int* slot_tok = basep + 8;         // 4096
    int* tok_slot = slot_tok + 4096;   // 4096
    float* tok_w  = (float*)(tok_slot + 4096);             // 4096
    u16* h   = (u16*)(ws + (1 << 16));                     // [4096][F] bf16 = 16.8 MB
    float* y = (float*)(ws + (1 << 16) + (size_t)4096 * F_DIM * 2);  // [4096][D] f32 = 16.8 MB

    router_kernel<<<1, 256, 0, stream>>>(gl, cnt, basep, slot_tok, tok_slot, tok_w);
    gemm1_kernel<<<dim3(F_DIM / BN, T_N / BM, E_N), 256, 0, stream>>>(hidden, W1, cnt, basep, slot_tok, h);
    gemm2_kernel<<<dim3(D_DIM / BN, T_N / BM, E_N), 256, 0, stream>>>(h, W2, cnt, basep, y);
    combine_kernel<<<T_N, 256, 0, stream>>>(y, tok_slot, tok_w, out);
}

// Round 2
// 275.218 us; speedup vs baseline: 1.1331x; 1.1331x over previous
//
#include <hip/hip_runtime.h>
#include <hip/hip_bf16.h>

#define E_N 8
#define D_DIM 1024
#define F_DIM 2048
#define T_N 2048
#define NSLOT 4096

typedef unsigned short u16;
typedef unsigned int u32;
typedef float floatx4 __attribute__((ext_vector_type(4)));
typedef short bf16x8v __attribute__((ext_vector_type(8)));

__device__ __forceinline__ u16 f2bf(float f) {
    union { float f; u32 u; } v; v.f = f;
    u32 r = v.u + 0x7FFFu + ((v.u >> 16) & 1u);   // RNE
    return (u16)(r >> 16);
}

// async global->LDS, 16B per lane; LDS dest = wave-uniform base + lane*16
__device__ __forceinline__ void gll16(const void* g, void* l) {
    __builtin_amdgcn_global_load_lds((const __attribute__((address_space(1))) void*)g,
                                     (__attribute__((address_space(3))) void*)l, 16, 0, 0);
}

// ---------------- Router: softmax -> top2 -> renorm, bucket by expert ----------------
__global__ void router_kernel(const float* __restrict__ gl,
                              int* __restrict__ cnt, int* __restrict__ base,
                              int* __restrict__ slot_tok, int* __restrict__ tok_slot,
                              float* __restrict__ tok_w) {
    __shared__ int scnt[E_N];
    __shared__ int sbase[E_N];
    const int tid = threadIdx.x;
    if (tid < E_N) scnt[tid] = 0;
    __syncthreads();
    int e0a[8], e1a[8], p0a[8], p1a[8];
    float w0a[8];
#pragma unroll
    for (int i = 0; i < 8; ++i) {
        const int t = tid + i * 256;
        const float4* gp = (const float4*)(gl + (size_t)t * E_N);
        const float4 x0 = gp[0], x1 = gp[1];
        float l[E_N] = {x0.x, x0.y, x0.z, x0.w, x1.x, x1.y, x1.z, x1.w};
        int e0 = 0; float m0 = l[0];
#pragma unroll
        for (int e = 1; e < E_N; ++e) if (l[e] > m0) { m0 = l[e]; e0 = e; }
        int e1 = -1; float m1 = -1e30f;
#pragma unroll
        for (int e = 0; e < E_N; ++e) if (e != e0 && l[e] > m1) { m1 = l[e]; e1 = e; }
        const float p = __expf(m1 - m0);       // <= 1
        w0a[i] = 1.0f / (1.0f + p);
        e0a[i] = e0; e1a[i] = e1;
        p0a[i] = atomicAdd(&scnt[e0], 1);
        p1a[i] = atomicAdd(&scnt[e1], 1);
    }
    __syncthreads();
    if (tid == 0) {
        int s = 0;
        for (int e = 0; e < E_N; ++e) { sbase[e] = s; base[e] = s; cnt[e] = scnt[e]; s += scnt[e]; }
    }
    __syncthreads();
#pragma unroll
    for (int i = 0; i < 8; ++i) {
        const int t = tid + i * 256;
        const int s0 = sbase[e0a[i]] + p0a[i];
        const int s1 = sbase[e1a[i]] + p1a[i];
        slot_tok[s0] = t; slot_tok[s1] = t;
        tok_slot[2 * t] = s0; tok_slot[2 * t + 1] = s1;
        tok_w[2 * t] = w0a[i]; tok_w[2 * t + 1] = 1.0f - w0a[i];
    }
}

// ---------------- Gather + cvt: Xg[slot][d] = bf16(hidden[slot_tok[slot]][d]) ----------------
__global__ __launch_bounds__(256) void gather_x_kernel(const float* __restrict__ X,
                                                       const int* __restrict__ slot_tok,
                                                       u16* __restrict__ Xg) {
    const int s = blockIdx.x, t = threadIdx.x;
    const int tok = slot_tok[s];
    const float4 v = *(const float4*)(X + (size_t)tok * D_DIM + t * 4);
    union { u16 o[4]; uint2 q; } u;
    u.o[0] = f2bf(v.x); u.o[1] = f2bf(v.y); u.o[2] = f2bf(v.z); u.o[3] = f2bf(v.w);
    *(uint2*)(Xg + (size_t)s * D_DIM + t * 4) = u.q;
}

// ---------------- Transpose + cvt: dst[e][c][r] = bf16(src[e][r][c]) ----------------
// coalesced loads along c; per-thread 32B stores (stride-K across lanes)
__global__ __launch_bounds__(256) void cvt_t_kernel(const float* __restrict__ src,
                                                    u16* __restrict__ dst, int R, int C) {
    const int e = blockIdx.z;
    const int r0 = blockIdx.y << 6, c0 = blockIdx.x << 6;
    const int t = threadIdx.x;
    const int n = t & 63, kq = t >> 6;
    const float* s = src + (size_t)e * R * C + (size_t)(r0 + kq * 16) * C + (c0 + n);
    union { u16 v[16]; uint4 q[2]; } u;
#pragma unroll
    for (int i = 0; i < 16; ++i) u.v[i] = f2bf(s[(size_t)i * C]);
    u16* d = dst + (size_t)e * R * C + (size_t)(c0 + n) * R + (r0 + kq * 16);
    *(uint4*)d = u.q[0];
    *(uint4*)(d + 8) = u.q[1];
}

// ---------------- Grouped GEMM, m97 structure + T2 swizzle ----------------
// A: [slots][KA] bf16 row-major. B: B^T rows [N][KB] bf16 (per-expert stride D*F).
// Tile 128x128, BK=64, 4 waves (2x2 of 64x64), 16x16x32 MFMA, 4x4 frags.
// LDS tiles [128][64] with byte-swizzle: slot ^= (row&7), applied at staging via
// pre-swizzled per-lane GLOBAL source offset (LDS dest stays linear) and at ds_read.
template<bool G1>
__global__ __launch_bounds__(256) void moe_gemm_kernel(
        const u16* __restrict__ A, const u16* __restrict__ B,
        const int* __restrict__ cnt, const int* __restrict__ basep,
        u16* __restrict__ hout, float* __restrict__ yout) {
    constexpr int KA = G1 ? D_DIM : F_DIM;   // A row stride (elements)
    constexpr int KB = KA;                   // B^T row stride
    constexpr int KIT = 16;                  // 1024/64 (G1) ; (2048/2)/64 (G2 split-K half)
    const int e  = G1 ? blockIdx.z : (blockIdx.z >> 1);
    const int kh = G1 ? 0 : (blockIdx.z & 1);
    const int mt = blockIdx.y;
    const int nt = blockIdx.x;
    const int cnt_e = cnt[e];
    if (mt * 128 >= cnt_e) return;
    const int m0 = basep[e] + mt * 128;
    const int vm = cnt_e - mt * 128;

    __shared__ __align__(16) u16 Alds[8192];
    __shared__ __align__(16) u16 Blds[8192];

    const int tid = threadIdx.x;
    const int wid = tid >> 6, lane = tid & 63;
    const int l3 = lane >> 3, l7 = lane & 7;
    const int stgRow = wid * 8 + l3;               // +c*32 per chunk
    const int stgCol = ((l7 ^ l3) << 3);           // pre-swizzled source col (elements)

    const u16* aS = A + (size_t)(m0 + stgRow) * KA + kh * (F_DIM / 2) + stgCol;
    const u16* bS = B + (size_t)e * ((size_t)D_DIM * F_DIM)
                      + (size_t)(nt * 128 + stgRow) * KB + kh * (F_DIM / 2) + stgCol;

    const int wm = (wid >> 1) * 64, wn = (wid & 1) * 64;
    const int lr = lane & 15, lq = lane >> 4;
    const int aoff = (wm + lr) * 64;               // + mi*1024 + sw
    const int boff = (wn + lr) * 64;
    const int sw0 = ((lq)     ^ l7) << 3;          // k-slice 0 swizzled slot
    const int sw1 = ((lq + 4) ^ l7) << 3;          // k-slice 1

    floatx4 acc[4][4];
    const floatx4 zero = {0.f, 0.f, 0.f, 0.f};
#pragma unroll
    for (int i = 0; i < 4; ++i)
#pragma unroll
        for (int j = 0; j < 4; ++j) acc[i][j] = zero;

    for (int kt = 0; kt < KIT; ++kt) {
#pragma unroll
        for (int c = 0; c < 4; ++c) {
            gll16(aS + (size_t)(c * 32) * KA, &Alds[c * 2048 + wid * 512]);
            gll16(bS + (size_t)(c * 32) * KB, &Blds[c * 2048 + wid * 512]);
        }
        aS += 64; bS += 64;
        __syncthreads();   // drains vmcnt -> LDS ready
#pragma unroll
        for (int ks = 0; ks < 2; ++ks) {
            const int sw = ks ? sw1 : sw0;
            bf16x8v af[4], bfv[4];
#pragma unroll
            for (int mi = 0; mi < 4; ++mi) af[mi]  = *(const bf16x8v*)&Alds[aoff + mi * 1024 + sw];
#pragma unroll
            for (int ni = 0; ni < 4; ++ni) bfv[ni] = *(const bf16x8v*)&Blds[boff + ni * 1024 + sw];
#pragma unroll
            for (int mi = 0; mi < 4; ++mi)
#pragma unroll
                for (int ni = 0; ni < 4; ++ni)
                    acc[mi][ni] = __builtin_amdgcn_mfma_f32_16x16x32_bf16(af[mi], bfv[ni], acc[mi][ni], 0, 0, 0);
        }
        __syncthreads();   // all frag reads done before next stage overwrites
    }

    if constexpr (G1) {
#pragma unroll
        for (int mi = 0; mi < 4; ++mi)
#pragma unroll
            for (int r = 0; r < 4; ++r) {
                const int rl = wm + mi * 16 + lq * 4 + r;
                if (rl < vm) {
                    u16* hp = hout + (size_t)(m0 + rl) * F_DIM + nt * 128 + wn + lr;
#pragma unroll
                    for (int ni = 0; ni < 4; ++ni) {
                        const float v = acc[mi][ni][r];
                        hp[ni * 16] = f2bf(v / (1.0f + __expf(-v)));
                    }
                }
            }
    } else {
        float* Y = yout + (size_t)kh * NSLOT * D_DIM;
#pragma unroll
        for (int mi = 0; mi < 4; ++mi)
#pragma unroll
            for (int r = 0; r < 4; ++r) {
                const int rl = wm + mi * 16 + lq * 4 + r;
                if (rl < vm) {
                    float* yp = Y + (size_t)(m0 + rl) * D_DIM + nt * 128 + wn + lr;
#pragma unroll
                    for (int ni = 0; ni < 4; ++ni) yp[ni * 16] = acc[mi][ni][r];
                }
            }
    }
}

// ---------------- Combine: out[t] = w0*(y0[s0]+y1[s0]) + w1*(y0[s1]+y1[s1]) ----------------
__global__ __launch_bounds__(256) void combine_kernel(const float* __restrict__ Y,
                                                      const int* __restrict__ tok_slot,
                                                      const float* __restrict__ tok_w,
                                                      float* __restrict__ out) {
    const int t = blockIdx.x, tid = threadIdx.x;
    const int s0 = tok_slot[2 * t], s1 = tok_slot[2 * t + 1];
    const float w0 = tok_w[2 * t], w1 = tok_w[2 * t + 1];
    const float* y0 = Y;
    const float* y1 = Y + (size_t)NSLOT * D_DIM;
    const float4 a0 = *(const float4*)(y0 + (size_t)s0 * D_DIM + tid * 4);
    const float4 a1 = *(const float4*)(y1 + (size_t)s0 * D_DIM + tid * 4);
    const float4 b0 = *(const float4*)(y0 + (size_t)s1 * D_DIM + tid * 4);
    const float4 b1 = *(const float4*)(y1 + (size_t)s1 * D_DIM + tid * 4);
    float4 o;
    o.x = w0 * (a0.x + a1.x) + w1 * (b0.x + b1.x);
    o.y = w0 * (a0.y + a1.y) + w1 * (b0.y + b1.y);
    o.z = w0 * (a0.z + a1.z) + w1 * (b0.z + b1.z);
    o.w = w0 * (a0.w + a1.w) + w1 * (b0.w + b1.w);
    *(float4*)(out + (size_t)t * D_DIM + tid * 4) = o;
}

extern "C" void kernel_launch(void* const* d_in, const int* in_sizes, int n_in,
                              void* d_out, int out_size, void* d_ws, size_t ws_size,
                              hipStream_t stream) {
    const float* hidden = (const float*)d_in[0];   // [B,S,D] f32
    const float* gl     = (const float*)d_in[1];   // [T,E]   f32
    const float* W1     = (const float*)d_in[2];   // [E,D,F] f32
    const float* W2     = (const float*)d_in[3];   // [E,F,D] f32
    float* out = (float*)d_out;

    char* ws = (char*)d_ws;
    int* m = (int*)ws;
    int* cnt      = m;
    int* basep    = m + 16;
    int* slot_tok = m + 32;            // 4096 ints
    int* tok_slot = m + 32 + 4096;     // 4096 ints
    float* tok_w  = (float*)(m + 32 + 8192);   // 4096 floats  (< 64 KB total meta)

    const size_t YBYTES = (size_t)2 * NSLOT * D_DIM * 4;            // 33.55 MB (2 split-K partials)
    const size_t HBYTES = (size_t)(NSLOT + 128) * F_DIM * 2;        // 17.3 MB (+slack rows)
    float* Y = (float*)(ws + (1 << 16));
    u16* h   = (u16*)(ws + (1 << 16) + YBYTES);
    char* regionR = ws + (1 << 16) + YBYTES + HBYTES;               // 42.2 MB region
    u16* W1T = (u16*)regionR;                                       // 33.55 MB
    u16* Xg  = (u16*)(regionR + (size_t)E_N * D_DIM * F_DIM * 2);   // 8.65 MB (+slack)
    u16* W2T = (u16*)regionR;                                       // reuses W1T+Xg after gemm1

    router_kernel<<<1, 256, 0, stream>>>(gl, cnt, basep, slot_tok, tok_slot, tok_w);
    gather_x_kernel<<<NSLOT, 256, 0, stream>>>(hidden, slot_tok, Xg);
    cvt_t_kernel<<<dim3(F_DIM / 64, D_DIM / 64, E_N), 256, 0, stream>>>(W1, W1T, D_DIM, F_DIM);
    moe_gemm_kernel<true><<<dim3(F_DIM / 128, 16, E_N), 256, 0, stream>>>(Xg, W1T, cnt, basep, h, nullptr);
    cvt_t_kernel<<<dim3(D_DIM / 64, F_DIM / 64, E_N), 256, 0, stream>>>(W2, W2T, F_DIM, D_DIM);
    moe_gemm_kernel<false><<<dim3(D_DIM / 128, 16, E_N * 2), 256, 0, stream>>>(h, W2T, cnt, basep, nullptr, Y);
    combine_kernel<<<T_N, 256, 0, stream>>>(Y, tok_slot, tok_w, out);
}

// Round 3
// 256.490 us; speedup vs baseline: 1.2158x; 1.0730x over previous
//
#include <hip/hip_runtime.h>
#include <hip/hip_bf16.h>

#define E_N 8
#define D_DIM 1024
#define F_DIM 2048
#define T_N 2048
#define NSLOT 4096

typedef unsigned short u16;
typedef unsigned int u32;
typedef float floatx4 __attribute__((ext_vector_type(4)));
typedef short bf16x8v __attribute__((ext_vector_type(8)));

__device__ __forceinline__ u16 f2bf(float f) {
    union { float f; u32 u; } v; v.f = f;
    u32 r = v.u + 0x7FFFu + ((v.u >> 16) & 1u);   // RNE
    return (u16)(r >> 16);
}

// async global->LDS, 16B per lane; LDS dest = wave-uniform base + lane*16
__device__ __forceinline__ void gll16(const void* g, void* l) {
    __builtin_amdgcn_global_load_lds((const __attribute__((address_space(1))) void*)g,
                                     (__attribute__((address_space(3))) void*)l, 16, 0, 0);
}

// ---------------- Router: softmax -> top2 -> renorm, bucket by expert ----------------
__global__ void router_kernel(const float* __restrict__ gl,
                              int* __restrict__ cnt, int* __restrict__ base,
                              int* __restrict__ slot_tok, int* __restrict__ tok_slot,
                              float* __restrict__ tok_w) {
    __shared__ int scnt[E_N];
    __shared__ int sbase[E_N];
    const int tid = threadIdx.x;
    if (tid < E_N) scnt[tid] = 0;
    __syncthreads();
    int e0a[8], e1a[8], p0a[8], p1a[8];
    float w0a[8];
#pragma unroll
    for (int i = 0; i < 8; ++i) {
        const int t = tid + i * 256;
        const float4* gp = (const float4*)(gl + (size_t)t * E_N);
        const float4 x0 = gp[0], x1 = gp[1];
        float l[E_N] = {x0.x, x0.y, x0.z, x0.w, x1.x, x1.y, x1.z, x1.w};
        int e0 = 0; float m0 = l[0];
#pragma unroll
        for (int e = 1; e < E_N; ++e) if (l[e] > m0) { m0 = l[e]; e0 = e; }
        int e1 = -1; float m1 = -1e30f;
#pragma unroll
        for (int e = 0; e < E_N; ++e) if (e != e0 && l[e] > m1) { m1 = l[e]; e1 = e; }
        const float p = __expf(m1 - m0);       // <= 1
        w0a[i] = 1.0f / (1.0f + p);
        e0a[i] = e0; e1a[i] = e1;
        p0a[i] = atomicAdd(&scnt[e0], 1);
        p1a[i] = atomicAdd(&scnt[e1], 1);
    }
    __syncthreads();
    if (tid == 0) {
        int s = 0;
        for (int e = 0; e < E_N; ++e) { sbase[e] = s; base[e] = s; cnt[e] = scnt[e]; s += scnt[e]; }
    }
    __syncthreads();
#pragma unroll
    for (int i = 0; i < 8; ++i) {
        const int t = tid + i * 256;
        const int s0 = sbase[e0a[i]] + p0a[i];
        const int s1 = sbase[e1a[i]] + p1a[i];
        slot_tok[s0] = t; slot_tok[s1] = t;
        tok_slot[2 * t] = s0; tok_slot[2 * t + 1] = s1;
        tok_w[2 * t] = w0a[i]; tok_w[2 * t + 1] = 1.0f - w0a[i];
    }
}

// ---------------- Gather + cvt: Xg[slot][d] = bf16(hidden[slot_tok[slot]][d]) ----------------
__global__ __launch_bounds__(256) void gather_x_kernel(const float* __restrict__ X,
                                                       const int* __restrict__ slot_tok,
                                                       u16* __restrict__ Xg) {
    const int s = blockIdx.x, t = threadIdx.x;
    const int tok = slot_tok[s];
    const float4 v = *(const float4*)(X + (size_t)tok * D_DIM + t * 4);
    union { u16 o[4]; uint2 q; } u;
    u.o[0] = f2bf(v.x); u.o[1] = f2bf(v.y); u.o[2] = f2bf(v.z); u.o[3] = f2bf(v.w);
    *(uint2*)(Xg + (size_t)s * D_DIM + t * 4) = u.q;
}

// ---------------- Transpose + cvt via LDS bounce: dst[e][c][r] = bf16(src[e][r][c]) ----------------
// 64x64 tile/block. Phase 1: coalesced float4 loads, swizzled scalar LDS writes (<=2-way).
// Phase 2: 16B swizzled LDS reads (bank-even), 128B-contiguous global store segments.
// Swizzle: elem(c,r) = c*64 + ((r>>3) ^ ((c>>2)&7))*8 + (r&7)  -- permutes aligned 16B groups.
__global__ __launch_bounds__(256) void cvt_t_kernel(const float* __restrict__ src,
                                                    u16* __restrict__ dst, int R, int C) {
    const int e = blockIdx.z;
    const int r0 = blockIdx.y << 6, c0 = blockIdx.x << 6;
    __shared__ __align__(16) u16 LT[4096];
    const int t = threadIdx.x;
    const int rowb = t >> 4;      // 0..15
    const int col4 = t & 15;      // c = col4*4 + j
    const float* sp = src + (size_t)e * R * C + (size_t)(r0 + rowb) * C + c0 + col4 * 4;
#pragma unroll
    for (int rr = 0; rr < 4; ++rr) {
        const float4 v = *(const float4*)(sp + (size_t)(rr * 16) * C);
        const int r = rowb + rr * 16;
        const int rg = r >> 3, ro = r & 7;
        u16 b[4] = {f2bf(v.x), f2bf(v.y), f2bf(v.z), f2bf(v.w)};
#pragma unroll
        for (int j = 0; j < 4; ++j) {
            const int c = col4 * 4 + j;
            LT[c * 64 + ((rg ^ ((c >> 2) & 7)) << 3) + ro] = b[j];
        }
    }
    __syncthreads();
    u16* dp = dst + (size_t)e * R * C;
#pragma unroll
    for (int i = 0; i < 2; ++i) {
        const int id = i * 256 + t;
        const int c = id >> 3, seg = id & 7;
        const uint4 q = *(const uint4*)&LT[c * 64 + ((seg ^ ((c >> 2) & 7)) << 3)];
        *(uint4*)(dp + (size_t)(c0 + c) * R + r0 + seg * 8) = q;
    }
}

// ---------------- Grouped GEMM, m97 structure + T2 swizzle ----------------
// A: [slots][KA] bf16 row-major. B: B^T rows [N][KB] bf16 (per-expert stride D*F).
// Tile 128x128, BK=64, 4 waves (2x2 of 64x64), 16x16x32 MFMA, 4x4 frags.
template<bool G1>
__global__ __launch_bounds__(256) void moe_gemm_kernel(
        const u16* __restrict__ A, const u16* __restrict__ B,
        const int* __restrict__ cnt, const int* __restrict__ basep,
        u16* __restrict__ hout, float* __restrict__ yout) {
    constexpr int KA = G1 ? D_DIM : F_DIM;   // A row stride (elements)
    constexpr int KB = KA;                   // B^T row stride
    constexpr int KIT = 16;                  // 1024/64 (G1) ; (2048/2)/64 (G2 split-K half)
    const int e  = G1 ? blockIdx.z : (blockIdx.z >> 1);
    const int kh = G1 ? 0 : (blockIdx.z & 1);
    const int mt = blockIdx.y;
    const int nt = blockIdx.x;
    const int cnt_e = cnt[e];
    if (mt * 128 >= cnt_e) return;
    const int m0 = basep[e] + mt * 128;
    const int vm = cnt_e - mt * 128;

    __shared__ __align__(16) u16 Alds[8192];
    __shared__ __align__(16) u16 Blds[8192];

    const int tid = threadIdx.x;
    const int wid = tid >> 6, lane = tid & 63;
    const int l3 = lane >> 3, l7 = lane & 7;
    const int stgRow = wid * 8 + l3;               // +c*32 per chunk
    const int stgCol = ((l7 ^ l3) << 3);           // pre-swizzled source col (elements)

    const u16* aS = A + (size_t)(m0 + stgRow) * KA + kh * (F_DIM / 2) + stgCol;
    const u16* bS = B + (size_t)e * ((size_t)D_DIM * F_DIM)
                      + (size_t)(nt * 128 + stgRow) * KB + kh * (F_DIM / 2) + stgCol;

    const int wm = (wid >> 1) * 64, wn = (wid & 1) * 64;
    const int lr = lane & 15, lq = lane >> 4;
    const int aoff = (wm + lr) * 64;               // + mi*1024 + sw
    const int boff = (wn + lr) * 64;
    const int sw0 = ((lq)     ^ l7) << 3;          // k-slice 0 swizzled slot
    const int sw1 = ((lq + 4) ^ l7) << 3;          // k-slice 1

    floatx4 acc[4][4];
    const floatx4 zero = {0.f, 0.f, 0.f, 0.f};
#pragma unroll
    for (int i = 0; i < 4; ++i)
#pragma unroll
        for (int j = 0; j < 4; ++j) acc[i][j] = zero;

    for (int kt = 0; kt < KIT; ++kt) {
#pragma unroll
        for (int c = 0; c < 4; ++c) {
            gll16(aS + (size_t)(c * 32) * KA, &Alds[c * 2048 + wid * 512]);
            gll16(bS + (size_t)(c * 32) * KB, &Blds[c * 2048 + wid * 512]);
        }
        aS += 64; bS += 64;
        __syncthreads();   // drains vmcnt -> LDS ready
#pragma unroll
        for (int ks = 0; ks < 2; ++ks) {
            const int sw = ks ? sw1 : sw0;
            bf16x8v af[4], bfv[4];
#pragma unroll
            for (int mi = 0; mi < 4; ++mi) af[mi]  = *(const bf16x8v*)&Alds[aoff + mi * 1024 + sw];
#pragma unroll
            for (int ni = 0; ni < 4; ++ni) bfv[ni] = *(const bf16x8v*)&Blds[boff + ni * 1024 + sw];
#pragma unroll
            for (int mi = 0; mi < 4; ++mi)
#pragma unroll
                for (int ni = 0; ni < 4; ++ni)
                    acc[mi][ni] = __builtin_amdgcn_mfma_f32_16x16x32_bf16(af[mi], bfv[ni], acc[mi][ni], 0, 0, 0);
        }
        __syncthreads();   // all frag reads done before next stage overwrites
    }

    if constexpr (G1) {
#pragma unroll
        for (int mi = 0; mi < 4; ++mi)
#pragma unroll
            for (int r = 0; r < 4; ++r) {
                const int rl = wm + mi * 16 + lq * 4 + r;
                if (rl < vm) {
                    u16* hp = hout + (size_t)(m0 + rl) * F_DIM + nt * 128 + wn + lr;
#pragma unroll
                    for (int ni = 0; ni < 4; ++ni) {
                        const float v = acc[mi][ni][r];
                        hp[ni * 16] = f2bf(v / (1.0f + __expf(-v)));
                    }
                }
            }
    } else {
        float* Y = yout + (size_t)kh * NSLOT * D_DIM;
#pragma unroll
        for (int mi = 0; mi < 4; ++mi)
#pragma unroll
            for (int r = 0; r < 4; ++r) {
                const int rl = wm + mi * 16 + lq * 4 + r;
                if (rl < vm) {
                    float* yp = Y + (size_t)(m0 + rl) * D_DIM + nt * 128 + wn + lr;
#pragma unroll
                    for (int ni = 0; ni < 4; ++ni) yp[ni * 16] = acc[mi][ni][r];
                }
            }
    }
}

// ---------------- Combine: out[t] = w0*(y0[s0]+y1[s0]) + w1*(y0[s1]+y1[s1]) ----------------
__global__ __launch_bounds__(256) void combine_kernel(const float* __restrict__ Y,
                                                      const int* __restrict__ tok_slot,
                                                      const float* __restrict__ tok_w,
                                                      float* __restrict__ out) {
    const int t = blockIdx.x, tid = threadIdx.x;
    const int s0 = tok_slot[2 * t], s1 = tok_slot[2 * t + 1];
    const float w0 = tok_w[2 * t], w1 = tok_w[2 * t + 1];
    const float* y0 = Y;
    const float* y1 = Y + (size_t)NSLOT * D_DIM;
    const float4 a0 = *(const float4*)(y0 + (size_t)s0 * D_DIM + tid * 4);
    const float4 a1 = *(const float4*)(y1 + (size_t)s0 * D_DIM + tid * 4);
    const float4 b0 = *(const float4*)(y0 + (size_t)s1 * D_DIM + tid * 4);
    const float4 b1 = *(const float4*)(y1 + (size_t)s1 * D_DIM + tid * 4);
    float4 o;
    o.x = w0 * (a0.x + a1.x) + w1 * (b0.x + b1.x);
    o.y = w0 * (a0.y + a1.y) + w1 * (b0.y + b1.y);
    o.z = w0 * (a0.z + a1.z) + w1 * (b0.z + b1.z);
    o.w = w0 * (a0.w + a1.w) + w1 * (b0.w + b1.w);
    *(float4*)(out + (size_t)t * D_DIM + tid * 4) = o;
}

extern "C" void kernel_launch(void* const* d_in, const int* in_sizes, int n_in,
                              void* d_out, int out_size, void* d_ws, size_t ws_size,
                              hipStream_t stream) {
    const float* hidden = (const float*)d_in[0];   // [B,S,D] f32
    const float* gl     = (const float*)d_in[1];   // [T,E]   f32
    const float* W1     = (const float*)d_in[2];   // [E,D,F] f32
    const float* W2     = (const float*)d_in[3];   // [E,F,D] f32
    float* out = (float*)d_out;

    char* ws = (char*)d_ws;
    int* m = (int*)ws;
    int* cnt      = m;
    int* basep    = m + 16;
    int* slot_tok = m + 32;            // 4096 ints
    int* tok_slot = m + 32 + 4096;     // 4096 ints
    float* tok_w  = (float*)(m + 32 + 8192);   // 4096 floats  (< 64 KB total meta)

    const size_t YBYTES = (size_t)2 * NSLOT * D_DIM * 4;            // 33.55 MB (2 split-K partials)
    const size_t HBYTES = (size_t)(NSLOT + 128) * F_DIM * 2;        // 17.3 MB (+slack rows)
    float* Y = (float*)(ws + (1 << 16));
    u16* h   = (u16*)(ws + (1 << 16) + YBYTES);
    char* regionR = ws + (1 << 16) + YBYTES + HBYTES;               // 42.2 MB region
    u16* W1T = (u16*)regionR;                                       // 33.55 MB
    u16* Xg  = (u16*)(regionR + (size_t)E_N * D_DIM * F_DIM * 2);   // 8.65 MB (+slack)
    u16* W2T = (u16*)regionR;                                       // reuses W1T+Xg after gemm1

    router_kernel<<<1, 256, 0, stream>>>(gl, cnt, basep, slot_tok, tok_slot, tok_w);
    gather_x_kernel<<<NSLOT, 256, 0, stream>>>(hidden, slot_tok, Xg);
    cvt_t_kernel<<<dim3(F_DIM / 64, D_DIM / 64, E_N), 256, 0, stream>>>(W1, W1T, D_DIM, F_DIM);
    moe_gemm_kernel<true><<<dim3(F_DIM / 128, 16, E_N), 256, 0, stream>>>(Xg, W1T, cnt, basep, h, nullptr);
    cvt_t_kernel<<<dim3(D_DIM / 64, F_DIM / 64, E_N), 256, 0, stream>>>(W2, W2T, F_DIM, D_DIM);
    moe_gemm_kernel<false><<<dim3(D_DIM / 128, 16, E_N * 2), 256, 0, stream>>>(h, W2T, cnt, basep, nullptr, Y);
    combine_kernel<<<T_N, 256, 0, stream>>>(Y, tok_slot, tok_w, out);
}